// Round 14
// baseline (6980.772 us; speedup 1.0000x reference)
//
#include <hip/hip_runtime.h>
#include <math.h>

#define B_  32
#define T_  512
#define H_  1024
#define G4_ 4096
#define NT  512
#define WROW 264    // load_wfrags bounce row pad

typedef __attribute__((ext_vector_type(8))) _Float16 f16x8;
typedef __attribute__((ext_vector_type(4))) float   f32x4;

__device__ __forceinline__ float hardsig(float z) {
    return fminf(fmaxf(0.2f * z + 0.5f, 0.0f), 1.0f);
}
__device__ __forceinline__ float fast_tanh(float x) {
    float ax = fabsf(x);
    float e  = __expf(-2.0f * ax);
    float t  = (1.0f - e) / (1.0f + e);
    return copysignf(t, x);
}
__device__ __forceinline__ unsigned ldA(const unsigned* p) {
    return __hip_atomic_load(p, __ATOMIC_RELAXED, __HIP_MEMORY_SCOPE_AGENT);
}
__device__ __forceinline__ void stA32(unsigned* p, unsigned v) {
    __hip_atomic_store(p, v, __ATOMIC_RELAXED, __HIP_MEMORY_SCOPE_AGENT);
}
__device__ __forceinline__ unsigned long long ldA64(const void* p) {
    return __hip_atomic_load((const unsigned long long*)p, __ATOMIC_RELAXED, __HIP_MEMORY_SCOPE_AGENT);
}
__device__ __forceinline__ void stA64(void* p, unsigned long long v) {
    __hip_atomic_store((unsigned long long*)p, v, __ATOMIC_RELAXED, __HIP_MEMORY_SCOPE_AGENT);
}
__device__ __forceinline__ float f16bits_to_f(unsigned short us) {
    _Float16 hf; __builtin_memcpy(&hf, &us, 2);
    return (float)hf;
}
__device__ __forceinline__ unsigned umin2(unsigned a, unsigned b) { return a < b ? a : b; }

// stage one 16B granule at flat byte-offset fb of a [32][1024] f16 matrix into
// fragment-order [mt][kiG][lane'][8] with XOR bank-swizzle (conflict-free).
__device__ __forceinline__ void stage_granule(const char* src, _Float16* dst, int fb) {
    uint4 v = *(const uint4*)(src + fb);
    const int r = fb >> 11, c0 = (fb & 2047) >> 1;
    const int kiG = c0 >> 5, q = (c0 >> 3) & 3;
    const int ln = (r & 15) + 16 * q;
    const int pl = ln ^ ((ln >> 3) & 6) ^ (kiG & 1);
    *(uint4*)&dst[(((r >> 4) * 32 + kiG) * 64 + pl) * 8] = v;
}

// Stage a [1024 k] x [64 gate-col] fp32 weight slice into per-wave MFMA B-fragments.
__device__ __forceinline__ void load_wfrags(const float* M, int colbase, int myrow,
                                            int koff, bool keep, f16x8* wf, _Float16* st) {
    for (int kc = 0; kc < 4; ++kc) {
        __syncthreads();
        #pragma unroll
        for (int it = 0; it < 4; ++it) {
            int id  = it * NT + (int)threadIdx.x;
            int kl  = id >> 3, gc8 = id & 7;
            int gcol = (gc8 >> 1) * 1024 + colbase + (gc8 & 1) * 8;
            const float* src = M + (size_t)(kc * 256 + kl) * G4_ + gcol;
            float4 v0 = *(const float4*)src;
            float4 v1 = *(const float4*)(src + 4);
            int rb = gc8 * 8;
            st[(rb+0)*WROW+kl]=(_Float16)v0.x; st[(rb+1)*WROW+kl]=(_Float16)v0.y;
            st[(rb+2)*WROW+kl]=(_Float16)v0.z; st[(rb+3)*WROW+kl]=(_Float16)v0.w;
            st[(rb+4)*WROW+kl]=(_Float16)v1.x; st[(rb+5)*WROW+kl]=(_Float16)v1.y;
            st[(rb+6)*WROW+kl]=(_Float16)v1.z; st[(rb+7)*WROW+kl]=(_Float16)v1.w;
        }
        __syncthreads();
        if (keep) {
            #pragma unroll
            for (int kj = 0; kj < 8; ++kj)
                wf[kc*8+kj] = *(const f16x8*)&st[myrow * WROW + kj * 32 + koff];
        }
    }
    __syncthreads();
}

// flags: dom0 @ ctr[db*2+wv] (128), dom1 @ ctr[128+db*2+wv] (128), engine @ ctr[384+e] (64)

__global__ __launch_bounds__(NT, 1)
void lstm14(const float* __restrict__ x,
            const float* __restrict__ W0, const float* __restrict__ U0, const float* __restrict__ b0,
            const float* __restrict__ W1, const float* __restrict__ U1, const float* __restrict__ b1,
            _Float16* __restrict__ h1,       // [T][B][H] fp16
            _Float16* __restrict__ h2,       // [T][B][H] fp16
            _Float16* __restrict__ xzr,      // [4][8][B][4H] fp16 ring (b0 folded)
            const _Float16* __restrict__ zp, // [B][H] fp16 zeros
            unsigned* __restrict__ ctr,
            float* __restrict__ out)         // [B][H] fp32
{
    __shared__ __align__(16) char smem[148480];

    const int tid = threadIdx.x, bid = blockIdx.x;
    const int w = tid >> 6, l = tid & 63;
    const int koff = (l >> 4) * 8;
    const int pl0 = l ^ ((l >> 3) & 6);    // XOR-swizzled fragment lane (kiG even)

    // ============================ xz ENGINE (bid 128..191) ============================
    if (bid >= 128) {
        _Float16* Wl = (_Float16*)smem;
        const int e = bid - 128, gbase = e * 64;
        for (int fi = tid; fi < 16384; fi += NT) {
            const int k = fi >> 4, rem = fi & 15;
            const float* src = W0 + (size_t)k * G4_ + gbase + rem * 4;
            float4 v = *(const float4*)src;
            const int kiG = k >> 5, jsub = 16 * ((k & 31) >> 3), e8 = k & 7;
            #pragma unroll
            for (int c = 0; c < 4; ++c) {
                const int j = rem * 4 + c, nf = j >> 4, lane = (j & 15) + jsub;
                float fv = (c == 0) ? v.x : (c == 1) ? v.y : (c == 2) ? v.z : v.w;
                Wl[((nf * 32 + kiG) * 64 + lane) * 8 + e8] = (_Float16)fv;
            }
        }
        float bb0[4];
        #pragma unroll
        for (int nf = 0; nf < 4; ++nf) bb0[nf] = b0[gbase + nf * 16 + (l & 15)];
        __syncthreads();

        for (int c = 0; c < 64; ++c) {
            if (c >= 4) {   // ring-slot reuse guard: dom0 consumed chunk c-4
                if (w == 0) {
                    const unsigned need = (unsigned)(8 * c - 24);
                    while (true) {
                        unsigned v = umin2(ldA(&ctr[2 * l]), ldA(&ctr[2 * l + 1]));
                        if (__all((int)(v >= need))) break;
                        __builtin_amdgcn_s_sleep(1);
                    }
                }
                __syncthreads();
            }
            f32x4 acc[2][4];
            #pragma unroll
            for (int p = 0; p < 2; ++p)
                #pragma unroll
                for (int nf = 0; nf < 4; ++nf) acc[p][nf] = (f32x4){0.f, 0.f, 0.f, 0.f};
            const float* xrow[2];
            #pragma unroll
            for (int p = 0; p < 2; ++p) {
                const int m = (w * 2 + p) * 16 + (l & 15);
                xrow[p] = x + ((size_t)(m & 31) * T_ + (8 * c + (m >> 5))) * 1024;
            }
            #pragma unroll 4
            for (int kiG = 0; kiG < 32; ++kiG) {
                const int kk = kiG * 32 + koff;
                f16x8 af[2];
                #pragma unroll
                for (int p = 0; p < 2; ++p) {
                    float4 v0 = *(const float4*)&xrow[p][kk];
                    float4 v1 = *(const float4*)&xrow[p][kk + 4];
                    af[p][0]=(_Float16)v0.x; af[p][1]=(_Float16)v0.y;
                    af[p][2]=(_Float16)v0.z; af[p][3]=(_Float16)v0.w;
                    af[p][4]=(_Float16)v1.x; af[p][5]=(_Float16)v1.y;
                    af[p][6]=(_Float16)v1.z; af[p][7]=(_Float16)v1.w;
                }
                #pragma unroll
                for (int nf = 0; nf < 4; ++nf) {
                    f16x8 bf = *(const f16x8*)&Wl[((nf * 32 + kiG) * 64 + l) * 8];
                    acc[0][nf] = __builtin_amdgcn_mfma_f32_16x16x32_f16(af[0], bf, acc[0][nf], 0, 0, 0);
                    acc[1][nf] = __builtin_amdgcn_mfma_f32_16x16x32_f16(af[1], bf, acc[1][nf], 0, 0, 0);
                }
            }
            #pragma unroll
            for (int p = 0; p < 2; ++p)
                #pragma unroll
                for (int nf = 0; nf < 4; ++nf)
                    #pragma unroll
                    for (int i = 0; i < 4; ++i) {
                        _Float16 hf = (_Float16)(acc[p][nf][i] + bb0[nf]);
                        unsigned short us; __builtin_memcpy(&us, &hf, 2);
                        unsigned up = us;
                        unsigned op = (unsigned)__shfl_xor((int)up, 1);
                        if (!(l & 1)) {
                            const int m = (w * 2 + p) * 16 + (l >> 4) * 4 + i;
                            size_t off = (((size_t)(c & 3) * 8 + (m >> 5)) * B_ + (m & 31)) * G4_
                                       + gbase + nf * 16 + ((l & 15) & ~1);
                            stA32((unsigned*)&xzr[off], up | (op << 16));
                        }
                    }
            asm volatile("s_waitcnt vmcnt(0)" ::: "memory");
            __syncthreads();
            if (tid == 0) stA32(&ctr[384 + e], (unsigned)(c + 1));
        }
        return;
    }

    // ============================ RECURRENCE DOMAINS (64+64 blocks x 16 cols) ============================
    const int dom = (bid >= 64);
    const int db  = bid & 63;
    const int jb  = db * 16;

    _Float16* stA = (_Float16*)smem;                 // 64 KiB frag-order A (h1 side)
    _Float16* stB = (_Float16*)(smem + 65536);       // 64 KiB (dom1: h2 side)
    float*    red = (float*)(smem + (dom ? 131072 : 65536));
    #define RED(slot, row, col) red[((slot) * 16 + (row)) * 17 + (col)]

    f16x8 wf[32];
    const int gq = w & 3;
    const int myrow = gq * 16 + (l & 15);
    if (dom == 0) {
        load_wfrags(U0, jb, myrow, koff, true, wf, stA);
    } else {
        const int rl0 = w >> 2;
        load_wfrags(W1, jb, myrow, koff, (rl0 == 0), wf, stA);
        load_wfrags(U1, jb, myrow, koff, (rl0 == 1), wf, stA);
    }

    const int cidx = w * 64 + l;
    const int cb = cidx >> 2, j4 = (cidx & 3) * 4;
    float creg[4] = {0.f, 0.f, 0.f, 0.f};
    float bias_[4][4];
    if (dom == 1 && w < 2) {
        #pragma unroll
        for (int g = 0; g < 4; ++g)
            #pragma unroll
            for (int c = 0; c < 4; ++c)
                bias_[g][c] = b1[(size_t)g * H_ + jb + j4 + c];
    }
    const int mt = w >> 2;          // dom0 m-tile
    const int rl = w >> 2;          // dom1 role
    const int wr = w & 3;           // dom1 within-role stage index

    for (int t = 0; t < T_; ++t) {
        // ---- per-wave poll of exactly the needed flag set (no S1 barrier) ----
        if (dom == 0) {
            if (t > 0) {
                while (true) {
                    unsigned v0 = umin2(ldA(&ctr[2 * l]), ldA(&ctr[2 * l + 1]));
                    if (__all((int)(v0 >= (unsigned)t))) break;
                    __builtin_amdgcn_s_sleep(1);
                }
            }
            if (w < 2) {   // combine waves also need the xz chunk
                const unsigned xt = (unsigned)((t >> 3) + 1);
                while (!__all((int)(ldA(&ctr[384 + l]) >= xt))) __builtin_amdgcn_s_sleep(1);
            }
        } else {
            if (rl == 0) {
                while (true) {
                    unsigned v0 = umin2(ldA(&ctr[2 * l]), ldA(&ctr[2 * l + 1]));
                    if (__all((int)(v0 >= (unsigned)(t + 1)))) break;
                    __builtin_amdgcn_s_sleep(1);
                }
            } else if (t > 0) {
                while (true) {
                    unsigned v1 = umin2(ldA(&ctr[128 + 2 * l]), ldA(&ctr[128 + 2 * l + 1]));
                    if (__all((int)(v1 >= (unsigned)t))) break;
                    __builtin_amdgcn_s_sleep(1);
                }
            }
        }
        asm volatile("" ::: "memory");

        // ---- per-wave staging into frag-order XOR-swizzled LDS ----
        if (dom == 0) {
            const char* src = t ? (const char*)(h1 + (size_t)(t - 1) * B_ * H_) : (const char*)zp;
            #pragma unroll
            for (int it = 0; it < 8; ++it)
                stage_granule(src, stA, tid * 16 + it * 8192);
        } else {
            const char* src = (rl == 0)
                ? (const char*)(h1 + (size_t)t * B_ * H_)
                : (t ? (const char*)(h2 + (size_t)(t - 1) * B_ * H_) : (const char*)zp);
            _Float16* dst = (rl == 0) ? stA : stB;
            #pragma unroll
            for (int it = 0; it < 16; ++it)
                stage_granule(src, dst, (wr * 64 + l) * 16 + it * 4096);
        }
        // dom0 combine waves: issue xz bypass loads (consumed after S3)
        unsigned long long xzq[4];
        if (dom == 0 && w < 2) {
            const size_t xbase = (((size_t)((t >> 3) & 3) * 8 + (t & 7)) * B_ + cb) * G4_ + jb + j4;
            #pragma unroll
            for (int gg = 0; gg < 4; ++gg) xzq[gg] = ldA64(&xzr[xbase + gg * 1024]);
        }
        __syncthreads();   // S2: stage visible

        // ---- MFMA: frag-order A reads (linear lane*16B + XOR; conflict-free) ----
        if (dom == 0) {
            f32x4 ac0 = {0,0,0,0}, ac1 = {0,0,0,0};
            #pragma unroll
            for (int k = 0; k < 32; k += 2) {
                ac0 = __builtin_amdgcn_mfma_f32_16x16x32_f16(
                    *(const f16x8*)&stA[((mt * 32 + k) * 64 + pl0) * 8], wf[k], ac0, 0, 0, 0);
                ac1 = __builtin_amdgcn_mfma_f32_16x16x32_f16(
                    *(const f16x8*)&stA[((mt * 32 + k + 1) * 64 + (pl0 ^ 1)) * 8], wf[k + 1], ac1, 0, 0, 0);
            }
            f32x4 acc = ac0 + ac1;
            #pragma unroll
            for (int i = 0; i < 4; ++i)
                RED(mt * 4 + gq, (l >> 4) * 4 + i, (l & 15)) = acc[i];
        } else {
            const _Float16* ab = (rl ? stB : stA);
            f32x4 ac0 = {0,0,0,0}, ac1 = {0,0,0,0};
            #pragma unroll
            for (int k = 0; k < 32; ++k) {
                const int pl = pl0 ^ (k & 1);
                f16x8 bfr = wf[k];
                ac0 = __builtin_amdgcn_mfma_f32_16x16x32_f16(
                    *(const f16x8*)&ab[((0 * 32 + k) * 64 + pl) * 8], bfr, ac0, 0, 0, 0);
                ac1 = __builtin_amdgcn_mfma_f32_16x16x32_f16(
                    *(const f16x8*)&ab[((1 * 32 + k) * 64 + pl) * 8], bfr, ac1, 0, 0, 0);
            }
            #pragma unroll
            for (int i = 0; i < 4; ++i) {
                RED(rl * 8 + 0 * 4 + gq, (l >> 4) * 4 + i, (l & 15)) = ac0[i];
                RED(rl * 8 + 1 * 4 + gq, (l >> 4) * 4 + i, (l & 15)) = ac1[i];
            }
        }
        __syncthreads();   // S3: red ready, stage buffers free

        // ---- combine + state + publish + ack + flag (waves 0..1) ----
        if (w < 2) {
            const int rmt = cb >> 4, row = cb & 15;
            unsigned long long pk = 0;
            float hv4[4];
            if (dom == 0) {
                asm volatile("s_waitcnt vmcnt(0)" ::: "memory");   // xz loads landed
                #pragma unroll
                for (int c = 0; c < 4; ++c) {
                    float z[4];
                    #pragma unroll
                    for (int gg = 0; gg < 4; ++gg) {
                        float xv = f16bits_to_f((unsigned short)((xzq[gg] >> (16 * c)) & 0xffffu));
                        z[gg] = RED(rmt * 4 + gg, row, j4 + c) + xv;   // b0 folded in xz
                    }
                    float ig = hardsig(z[0]), fg = hardsig(z[1]);
                    float gv = fast_tanh(z[2]), og = hardsig(z[3]);
                    creg[c] = fg * creg[c] + ig * gv;
                    hv4[c] = og * fast_tanh(creg[c]);
                    _Float16 hf = (_Float16)hv4[c];
                    unsigned short us; __builtin_memcpy(&us, &hf, 2);
                    pk |= ((unsigned long long)us) << (16 * c);
                }
                stA64(&h1[((size_t)t * B_ + cb) * H_ + jb + j4], pk);
                asm volatile("s_waitcnt vmcnt(0)" ::: "memory");   // publish ACKed at LLC
                if (l == 0) stA32(&ctr[db * 2 + w], (unsigned)(t + 1));
            } else {
                #pragma unroll
                for (int c = 0; c < 4; ++c) {
                    float z[4];
                    #pragma unroll
                    for (int gg = 0; gg < 4; ++gg)
                        z[gg] = RED(0 + rmt * 4 + gg, row, j4 + c)
                              + RED(8 + rmt * 4 + gg, row, j4 + c) + bias_[gg][c];
                    float ig = hardsig(z[0]), fg = hardsig(z[1]);
                    float gv = fast_tanh(z[2]), og = hardsig(z[3]);
                    creg[c] = fg * creg[c] + ig * gv;
                    hv4[c] = og * fast_tanh(creg[c]);
                    _Float16 hf = (_Float16)hv4[c];
                    unsigned short us; __builtin_memcpy(&us, &hf, 2);
                    pk |= ((unsigned long long)us) << (16 * c);
                }
                stA64(&h2[((size_t)t * B_ + cb) * H_ + jb + j4], pk);
                if (t == T_ - 1)
                    *(float4*)&out[(size_t)cb * H_ + jb + j4] = make_float4(hv4[0], hv4[1], hv4[2], hv4[3]);
                asm volatile("s_waitcnt vmcnt(0)" ::: "memory");
                if (l == 0) stA32(&ctr[128 + db * 2 + w], (unsigned)(t + 1));
            }
        }
    }
}

extern "C" void kernel_launch(void* const* d_in, const int* in_sizes, int n_in,
                              void* d_out, int out_size, void* d_ws, size_t ws_size,
                              hipStream_t stream) {
    const float* x  = (const float*)d_in[0];
    const float* W0 = (const float*)d_in[1];
    const float* U0 = (const float*)d_in[2];
    const float* b0 = (const float*)d_in[3];
    const float* W1 = (const float*)d_in[4];
    const float* U1 = (const float*)d_in[5];
    const float* b1 = (const float*)d_in[6];
    float* out = (float*)d_out;

    char* ws = (char*)d_ws;
    const size_t off_h1 = 0;          // 32 MiB  h1 fp16 [T][B][H]
    const size_t off_h2 = 33554432;   // 32 MiB  h2 fp16 [T][B][H]
    const size_t off_xz = 67108864;   //  8 MiB  xz ring fp16
    const size_t off_zp = 75497472;   // 64 KiB  fp16 zeros
    const size_t off_ct = 75563008;   //  8 KiB  flags

    _Float16* h1  = (_Float16*)(ws + off_h1);
    _Float16* h2  = (_Float16*)(ws + off_h2);
    _Float16* xzr = (_Float16*)(ws + off_xz);
    _Float16* zp  = (_Float16*)(ws + off_zp);
    unsigned* ctr = (unsigned*)(ws + off_ct);

    // zero zp + flags every launch (graph-capture safe)
    hipMemsetAsync(ws + off_zp, 0, 65536 + 8192, stream);

    hipLaunchKernelGGL(lstm14, dim3(192), dim3(NT), 0, stream,
                       x, W0, U0, b0, W1, U1, b1,
                       h1, h2, xzr, zp, ctr, out);
}

// Round 15
// 6796.603 us; speedup vs baseline: 1.0271x; 1.0271x over previous
//
#include <hip/hip_runtime.h>
#include <math.h>

#define B_  32
#define T_  512
#define H_  1024
#define G4_ 4096
#define NT  512
#define WROW 264    // load_wfrags bounce row pad

typedef __attribute__((ext_vector_type(8))) _Float16 f16x8;
typedef __attribute__((ext_vector_type(4))) float   f32x4;

__device__ __forceinline__ float hardsig(float z) {
    return fminf(fmaxf(0.2f * z + 0.5f, 0.0f), 1.0f);
}
__device__ __forceinline__ float fast_tanh(float x) {
    float ax = fabsf(x);
    float e  = __expf(-2.0f * ax);
    float t  = (1.0f - e) / (1.0f + e);
    return copysignf(t, x);
}
__device__ __forceinline__ unsigned ldA(const unsigned* p) {
    return __hip_atomic_load(p, __ATOMIC_RELAXED, __HIP_MEMORY_SCOPE_AGENT);
}
__device__ __forceinline__ void stA32(unsigned* p, unsigned v) {
    __hip_atomic_store(p, v, __ATOMIC_RELAXED, __HIP_MEMORY_SCOPE_AGENT);
}
__device__ __forceinline__ unsigned long long ldA64(const void* p) {
    return __hip_atomic_load((const unsigned long long*)p, __ATOMIC_RELAXED, __HIP_MEMORY_SCOPE_AGENT);
}
__device__ __forceinline__ void stA64(void* p, unsigned long long v) {
    __hip_atomic_store((unsigned long long*)p, v, __ATOMIC_RELAXED, __HIP_MEMORY_SCOPE_AGENT);
}
__device__ __forceinline__ float f16bits_to_f(unsigned short us) {
    _Float16 hf; __builtin_memcpy(&hf, &us, 2);
    return (float)hf;
}
__device__ __forceinline__ unsigned umin2(unsigned a, unsigned b) { return a < b ? a : b; }

// One staging pass over the granules in `pend` (8 granules x 16B per thread,
// [32][1024] f16 src -> frag-order [mt][kiG][lane'][8] XOR-swizzled LDS).
// Sentinel (0xFFFFFFFF in either 8B half's low dword) -> granule stays pending.
// First pass uses plain cached loads; retries MUST bypass (stale-L2 trap).
template<bool BYPASS>
__device__ __forceinline__ unsigned stage_pass(const char* src, _Float16* dst,
                                               int tid, unsigned pend) {
    unsigned np = 0;
    #pragma unroll
    for (int it = 0; it < 8; ++it) if (pend & (1u << it)) {
        const int fb = tid * 16 + it * 8192;
        uint4 v;
        if (BYPASS) {
            unsigned long long a = ldA64(src + fb), b = ldA64(src + fb + 8);
            v.x = (unsigned)a; v.y = (unsigned)(a >> 32);
            v.z = (unsigned)b; v.w = (unsigned)(b >> 32);
        } else {
            v = *(const uint4*)(src + fb);
        }
        if (v.x == 0xFFFFFFFFu || v.z == 0xFFFFFFFFu) { np |= (1u << it); continue; }
        const int r = fb >> 11, c0 = (fb & 2047) >> 1;
        const int kiG = c0 >> 5, q = (c0 >> 3) & 3;
        const int ln = (r & 15) + 16 * q;
        const int pl = ln ^ ((ln >> 3) & 6) ^ (kiG & 1);
        *(uint4*)&dst[(((r >> 4) * 32 + kiG) * 64 + pl) * 8] = v;
    }
    return np;
}
__device__ __forceinline__ void stage_full(const char* src, _Float16* dst, int tid) {
    unsigned pend = stage_pass<false>(src, dst, tid, 0xFFu);
    while (pend) pend = stage_pass<true>(src, dst, tid, pend);
}

// Stage a [1024 k] x [64 gate-col] fp32 weight slice into per-wave MFMA B-fragments.
__device__ __forceinline__ void load_wfrags(const float* M, int colbase, int myrow,
                                            int koff, bool keep, f16x8* wf, _Float16* st) {
    for (int kc = 0; kc < 4; ++kc) {
        __syncthreads();
        #pragma unroll
        for (int it = 0; it < 4; ++it) {
            int id  = it * NT + (int)threadIdx.x;
            int kl  = id >> 3, gc8 = id & 7;
            int gcol = (gc8 >> 1) * 1024 + colbase + (gc8 & 1) * 8;
            const float* src = M + (size_t)(kc * 256 + kl) * G4_ + gcol;
            float4 v0 = *(const float4*)src;
            float4 v1 = *(const float4*)(src + 4);
            int rb = gc8 * 8;
            st[(rb+0)*WROW+kl]=(_Float16)v0.x; st[(rb+1)*WROW+kl]=(_Float16)v0.y;
            st[(rb+2)*WROW+kl]=(_Float16)v0.z; st[(rb+3)*WROW+kl]=(_Float16)v0.w;
            st[(rb+4)*WROW+kl]=(_Float16)v1.x; st[(rb+5)*WROW+kl]=(_Float16)v1.y;
            st[(rb+6)*WROW+kl]=(_Float16)v1.z; st[(rb+7)*WROW+kl]=(_Float16)v1.w;
        }
        __syncthreads();
        if (keep) {
            #pragma unroll
            for (int kj = 0; kj < 8; ++kj)
                wf[kc*8+kj] = *(const f16x8*)&st[myrow * WROW + kj * 32 + koff];
        }
    }
    __syncthreads();
}

// flags: dom0 @ ctr[db*2+wv] (128), dom1 @ ctr[128+db*2+wv] (128), engine @ ctr[384+e] (64)

__global__ __launch_bounds__(NT, 1)
void lstm15(const float* __restrict__ x,
            const float* __restrict__ W0, const float* __restrict__ U0, const float* __restrict__ b0,
            const float* __restrict__ W1, const float* __restrict__ U1, const float* __restrict__ b1,
            _Float16* __restrict__ h1,       // [T][B][H] fp16, 0xFF-sentinel at launch
            _Float16* __restrict__ h2,       // [T][B][H] fp16, 0xFF-sentinel at launch
            _Float16* __restrict__ xzr,      // [4][8][B][4H] fp16 ring (b0 folded)
            const _Float16* __restrict__ zp, // [B][H] fp16 zeros
            unsigned* __restrict__ ctr,
            float* __restrict__ out)         // [B][H] fp32
{
    __shared__ __align__(16) char smem[148480];

    const int tid = threadIdx.x, bid = blockIdx.x;
    const int w = tid >> 6, l = tid & 63;
    const int koff = (l >> 4) * 8;
    const int pl0 = l ^ ((l >> 3) & 6);    // XOR-swizzled fragment lane (kiG even)

    // ============================ xz ENGINE (bid 128..191) ============================
    if (bid >= 128) {
        _Float16* Wl = (_Float16*)smem;
        const int e = bid - 128, gbase = e * 64;
        for (int fi = tid; fi < 16384; fi += NT) {
            const int k = fi >> 4, rem = fi & 15;
            const float* src = W0 + (size_t)k * G4_ + gbase + rem * 4;
            float4 v = *(const float4*)src;
            const int kiG = k >> 5, jsub = 16 * ((k & 31) >> 3), e8 = k & 7;
            #pragma unroll
            for (int c = 0; c < 4; ++c) {
                const int j = rem * 4 + c, nf = j >> 4, lane = (j & 15) + jsub;
                float fv = (c == 0) ? v.x : (c == 1) ? v.y : (c == 2) ? v.z : v.w;
                Wl[((nf * 32 + kiG) * 64 + lane) * 8 + e8] = (_Float16)fv;
            }
        }
        float bb0[4];
        #pragma unroll
        for (int nf = 0; nf < 4; ++nf) bb0[nf] = b0[gbase + nf * 16 + (l & 15)];
        __syncthreads();

        for (int c = 0; c < 64; ++c) {
            if (c >= 4) {   // ring-slot reuse guard: dom0 consumed chunk c-4
                if (w == 0) {
                    const unsigned need = (unsigned)(8 * c - 24);
                    while (true) {
                        unsigned v = umin2(ldA(&ctr[2 * l]), ldA(&ctr[2 * l + 1]));
                        if (__all((int)(v >= need))) break;
                        __builtin_amdgcn_s_sleep(1);
                    }
                }
                __syncthreads();
            }
            f32x4 acc[2][4];
            #pragma unroll
            for (int p = 0; p < 2; ++p)
                #pragma unroll
                for (int nf = 0; nf < 4; ++nf) acc[p][nf] = (f32x4){0.f, 0.f, 0.f, 0.f};
            const float* xrow[2];
            #pragma unroll
            for (int p = 0; p < 2; ++p) {
                const int m = (w * 2 + p) * 16 + (l & 15);
                xrow[p] = x + ((size_t)(m & 31) * T_ + (8 * c + (m >> 5))) * 1024;
            }
            #pragma unroll 4
            for (int kiG = 0; kiG < 32; ++kiG) {
                const int kk = kiG * 32 + koff;
                f16x8 af[2];
                #pragma unroll
                for (int p = 0; p < 2; ++p) {
                    float4 v0 = *(const float4*)&xrow[p][kk];
                    float4 v1 = *(const float4*)&xrow[p][kk + 4];
                    af[p][0]=(_Float16)v0.x; af[p][1]=(_Float16)v0.y;
                    af[p][2]=(_Float16)v0.z; af[p][3]=(_Float16)v0.w;
                    af[p][4]=(_Float16)v1.x; af[p][5]=(_Float16)v1.y;
                    af[p][6]=(_Float16)v1.z; af[p][7]=(_Float16)v1.w;
                }
                #pragma unroll
                for (int nf = 0; nf < 4; ++nf) {
                    f16x8 bf = *(const f16x8*)&Wl[((nf * 32 + kiG) * 64 + l) * 8];
                    acc[0][nf] = __builtin_amdgcn_mfma_f32_16x16x32_f16(af[0], bf, acc[0][nf], 0, 0, 0);
                    acc[1][nf] = __builtin_amdgcn_mfma_f32_16x16x32_f16(af[1], bf, acc[1][nf], 0, 0, 0);
                }
            }
            #pragma unroll
            for (int p = 0; p < 2; ++p)
                #pragma unroll
                for (int nf = 0; nf < 4; ++nf)
                    #pragma unroll
                    for (int i = 0; i < 4; ++i) {
                        _Float16 hf = (_Float16)(acc[p][nf][i] + bb0[nf]);
                        unsigned short us; __builtin_memcpy(&us, &hf, 2);
                        unsigned up = us;
                        unsigned op = (unsigned)__shfl_xor((int)up, 1);
                        if (!(l & 1)) {
                            const int m = (w * 2 + p) * 16 + (l >> 4) * 4 + i;
                            size_t off = (((size_t)(c & 3) * 8 + (m >> 5)) * B_ + (m & 31)) * G4_
                                       + gbase + nf * 16 + ((l & 15) & ~1);
                            stA32((unsigned*)&xzr[off], up | (op << 16));
                        }
                    }
            asm volatile("s_waitcnt vmcnt(0)" ::: "memory");
            __syncthreads();
            if (tid == 0) stA32(&ctr[384 + e], (unsigned)(c + 1));
        }
        return;
    }

    // ============================ RECURRENCE DOMAINS (64+64 blocks x 16 cols) ============================
    const int dom = (bid >= 64);
    const int db  = bid & 63;
    const int jb  = db * 16;

    _Float16* stA = (_Float16*)smem;                 // 64 KiB frag-order A (h1 side)
    _Float16* stB = (_Float16*)(smem + 65536);       // 64 KiB (dom1: h2 side)
    float*    red = (float*)(smem + (dom ? 131072 : 65536));
    #define RED(slot, row, col) red[((slot) * 16 + (row)) * 17 + (col)]

    f16x8 wf[32];
    const int gq = w & 3;
    const int myrow = gq * 16 + (l & 15);
    if (dom == 0) {
        load_wfrags(U0, jb, myrow, koff, true, wf, stA);
    } else {
        const int rl0 = w >> 2;
        load_wfrags(W1, jb, myrow, koff, (rl0 == 0), wf, stA);
        load_wfrags(U1, jb, myrow, koff, (rl0 == 1), wf, stA);
    }

    const int cidx = w * 64 + l;
    const int cb = cidx >> 2, j4 = (cidx & 3) * 4;
    float creg[4] = {0.f, 0.f, 0.f, 0.f};
    float bias_[4][4];
    if (dom == 1 && w < 2) {
        #pragma unroll
        for (int g = 0; g < 4; ++g)
            #pragma unroll
            for (int c = 0; c < 4; ++c)
                bias_[g][c] = b1[(size_t)g * H_ + jb + j4 + c];
    }
    const int mt = w >> 2;          // dom0 m-tile
    const int rl = w >> 2;          // dom1 role

    for (int t = 0; t < T_; ++t) {
        // ---- single polling wave (wave 0), lane-parallel over flag sets ----
        if (w == 0) {
            if (dom == 0) {
                const unsigned xt = (unsigned)((t >> 3) + 1);
                while (true) {
                    bool ok = (ldA(&ctr[384 + l]) >= xt);
                    if (t > 0) {
                        unsigned v0 = umin2(ldA(&ctr[2 * l]), ldA(&ctr[2 * l + 1]));
                        ok = ok && (v0 >= (unsigned)t);
                    }
                    if (__all((int)ok)) break;
                    __builtin_amdgcn_s_sleep(1);
                }
            } else {
                while (true) {
                    unsigned v0 = umin2(ldA(&ctr[2 * l]), ldA(&ctr[2 * l + 1]));
                    bool ok = (v0 >= (unsigned)(t + 1));
                    if (t > 0) {
                        unsigned v1 = umin2(ldA(&ctr[128 + 2 * l]), ldA(&ctr[128 + 2 * l + 1]));
                        ok = ok && (v1 >= (unsigned)t);
                    }
                    if (__all((int)ok)) break;
                    __builtin_amdgcn_s_sleep(1);
                }
            }
        }
        __syncthreads();   // S1: dependencies signalled, staging buffers free

        // ---- block-cooperative frag-order staging (sentinel-checked) ----
        if (dom == 0) {
            const char* src = t ? (const char*)(h1 + (size_t)(t - 1) * B_ * H_) : (const char*)zp;
            stage_full(src, stA, tid);
        } else {
            const char* s1 = (const char*)(h1 + (size_t)t * B_ * H_);
            const char* s2 = t ? (const char*)(h2 + (size_t)(t - 1) * B_ * H_) : (const char*)zp;
            stage_full(s1, stA, tid);
            stage_full(s2, stB, tid);
        }
        // dom0 combine waves: issue xz bypass loads (consumed after S3)
        unsigned long long xzq[4];
        if (dom == 0 && w < 2) {
            const size_t xbase = (((size_t)((t >> 3) & 3) * 8 + (t & 7)) * B_ + cb) * G4_ + jb + j4;
            #pragma unroll
            for (int gg = 0; gg < 4; ++gg) xzq[gg] = ldA64(&xzr[xbase + gg * 1024]);
        }
        __syncthreads();   // S2: stage visible

        // ---- MFMA: frag-order A reads (linear lane*16B + XOR; conflict-free) ----
        if (dom == 0) {
            f32x4 ac0 = {0,0,0,0}, ac1 = {0,0,0,0};
            #pragma unroll
            for (int k = 0; k < 32; k += 2) {
                ac0 = __builtin_amdgcn_mfma_f32_16x16x32_f16(
                    *(const f16x8*)&stA[((mt * 32 + k) * 64 + pl0) * 8], wf[k], ac0, 0, 0, 0);
                ac1 = __builtin_amdgcn_mfma_f32_16x16x32_f16(
                    *(const f16x8*)&stA[((mt * 32 + k + 1) * 64 + (pl0 ^ 1)) * 8], wf[k + 1], ac1, 0, 0, 0);
            }
            f32x4 acc = ac0 + ac1;
            #pragma unroll
            for (int i = 0; i < 4; ++i)
                RED(mt * 4 + gq, (l >> 4) * 4 + i, (l & 15)) = acc[i];
        } else {
            const _Float16* ab = (rl ? stB : stA);
            f32x4 ac0 = {0,0,0,0}, ac1 = {0,0,0,0};
            #pragma unroll
            for (int k = 0; k < 32; ++k) {
                const int pl = pl0 ^ (k & 1);
                f16x8 bfr = wf[k];
                ac0 = __builtin_amdgcn_mfma_f32_16x16x32_f16(
                    *(const f16x8*)&ab[((0 * 32 + k) * 64 + pl) * 8], bfr, ac0, 0, 0, 0);
                ac1 = __builtin_amdgcn_mfma_f32_16x16x32_f16(
                    *(const f16x8*)&ab[((1 * 32 + k) * 64 + pl) * 8], bfr, ac1, 0, 0, 0);
            }
            #pragma unroll
            for (int i = 0; i < 4; ++i) {
                RED(rl * 8 + 0 * 4 + gq, (l >> 4) * 4 + i, (l & 15)) = ac0[i];
                RED(rl * 8 + 1 * 4 + gq, (l >> 4) * 4 + i, (l & 15)) = ac1[i];
            }
        }
        __syncthreads();   // S3: red ready, stage buffers free

        // ---- combine + state + publish (NO ACK: sentinel covers the race) ----
        if (w < 2) {
            const int rmt = cb >> 4, row = cb & 15;
            unsigned long long pk = 0;
            float hv4[4];
            if (dom == 0) {
                asm volatile("s_waitcnt vmcnt(0)" ::: "memory");   // own xz loads landed
                #pragma unroll
                for (int c = 0; c < 4; ++c) {
                    float z[4];
                    #pragma unroll
                    for (int gg = 0; gg < 4; ++gg) {
                        float xv = f16bits_to_f((unsigned short)((xzq[gg] >> (16 * c)) & 0xffffu));
                        z[gg] = RED(rmt * 4 + gg, row, j4 + c) + xv;   // b0 folded in xz
                    }
                    float ig = hardsig(z[0]), fg = hardsig(z[1]);
                    float gv = fast_tanh(z[2]), og = hardsig(z[3]);
                    creg[c] = fg * creg[c] + ig * gv;
                    hv4[c] = og * fast_tanh(creg[c]);
                    _Float16 hf = (_Float16)hv4[c];
                    unsigned short us; __builtin_memcpy(&us, &hf, 2);
                    pk |= ((unsigned long long)us) << (16 * c);
                }
                stA64(&h1[((size_t)t * B_ + cb) * H_ + jb + j4], pk);
                asm volatile("" ::: "memory");   // pin compiler order: data store before flag
                if (l == 0) stA32(&ctr[db * 2 + w], (unsigned)(t + 1));
            } else {
                #pragma unroll
                for (int c = 0; c < 4; ++c) {
                    float z[4];
                    #pragma unroll
                    for (int gg = 0; gg < 4; ++gg)
                        z[gg] = RED(0 + rmt * 4 + gg, row, j4 + c)
                              + RED(8 + rmt * 4 + gg, row, j4 + c) + bias_[gg][c];
                    float ig = hardsig(z[0]), fg = hardsig(z[1]);
                    float gv = fast_tanh(z[2]), og = hardsig(z[3]);
                    creg[c] = fg * creg[c] + ig * gv;
                    hv4[c] = og * fast_tanh(creg[c]);
                    _Float16 hf = (_Float16)hv4[c];
                    unsigned short us; __builtin_memcpy(&us, &hf, 2);
                    pk |= ((unsigned long long)us) << (16 * c);
                }
                stA64(&h2[((size_t)t * B_ + cb) * H_ + jb + j4], pk);
                if (t == T_ - 1)
                    *(float4*)&out[(size_t)cb * H_ + jb + j4] = make_float4(hv4[0], hv4[1], hv4[2], hv4[3]);
                asm volatile("" ::: "memory");
                if (l == 0) stA32(&ctr[128 + db * 2 + w], (unsigned)(t + 1));
            }
        }
    }
}

extern "C" void kernel_launch(void* const* d_in, const int* in_sizes, int n_in,
                              void* d_out, int out_size, void* d_ws, size_t ws_size,
                              hipStream_t stream) {
    const float* x  = (const float*)d_in[0];
    const float* W0 = (const float*)d_in[1];
    const float* U0 = (const float*)d_in[2];
    const float* b0 = (const float*)d_in[3];
    const float* W1 = (const float*)d_in[4];
    const float* U1 = (const float*)d_in[5];
    const float* b1 = (const float*)d_in[6];
    float* out = (float*)d_out;

    char* ws = (char*)d_ws;
    const size_t off_h1 = 0;          // 32 MiB  h1 fp16 [T][B][H]  (0xFF sentinel)
    const size_t off_h2 = 33554432;   // 32 MiB  h2 fp16 [T][B][H]  (0xFF sentinel)
    const size_t off_xz = 67108864;   //  8 MiB  xz ring fp16
    const size_t off_zp = 75497472;   // 64 KiB  fp16 zeros
    const size_t off_ct = 75563008;   //  8 KiB  flags

    _Float16* h1  = (_Float16*)(ws + off_h1);
    _Float16* h2  = (_Float16*)(ws + off_h2);
    _Float16* xzr = (_Float16*)(ws + off_xz);
    _Float16* zp  = (_Float16*)(ws + off_zp);
    unsigned* ctr = (unsigned*)(ws + off_ct);

    // sentinel-fill h1/h2; zero zp + flags (graph-capture safe, every launch)
    hipMemsetAsync(ws, 0xFF, 67108864, stream);
    hipMemsetAsync(ws + off_zp, 0, 65536 + 8192, stream);

    hipLaunchKernelGGL(lstm15, dim3(192), dim3(NT), 0, stream,
                       x, W0, U0, b0, W1, U1, b1,
                       h1, h2, xzr, zp, ctr, out);
}

// Round 16
// 4661.550 us; speedup vs baseline: 1.4975x; 1.4580x over previous
//
#include <hip/hip_runtime.h>
#include <math.h>

#define B_  32
#define T_  512
#define H_  1024
#define G4_ 4096
#define NT  512
#define WROW 264    // load_wfrags bounce row pad

typedef __attribute__((ext_vector_type(8))) _Float16 f16x8;
typedef __attribute__((ext_vector_type(4))) float   f32x4;

__device__ __forceinline__ float hardsig(float z) {
    return fminf(fmaxf(0.2f * z + 0.5f, 0.0f), 1.0f);
}
__device__ __forceinline__ float fast_tanh(float x) {
    float ax = fabsf(x);
    float e  = __expf(-2.0f * ax);
    float t  = (1.0f - e) / (1.0f + e);
    return copysignf(t, x);
}
__device__ __forceinline__ unsigned ldA(const unsigned* p) {
    return __hip_atomic_load(p, __ATOMIC_RELAXED, __HIP_MEMORY_SCOPE_AGENT);
}
__device__ __forceinline__ void stA32(unsigned* p, unsigned v) {
    __hip_atomic_store(p, v, __ATOMIC_RELAXED, __HIP_MEMORY_SCOPE_AGENT);
}
__device__ __forceinline__ unsigned long long ldA64(const void* p) {
    return __hip_atomic_load((const unsigned long long*)p, __ATOMIC_RELAXED, __HIP_MEMORY_SCOPE_AGENT);
}
__device__ __forceinline__ void stA64(void* p, unsigned long long v) {
    __hip_atomic_store((unsigned long long*)p, v, __ATOMIC_RELAXED, __HIP_MEMORY_SCOPE_AGENT);
}
__device__ __forceinline__ float f16bits_to_f(unsigned short us) {
    _Float16 hf; __builtin_memcpy(&hf, &us, 2);
    return (float)hf;
}
__device__ __forceinline__ unsigned umin2(unsigned a, unsigned b) { return a < b ? a : b; }

// stage one 16B granule at flat byte-offset fb of a [32][1024] f16 matrix into
// frag-order [mt][kiG][lane'][8] with XOR bank-swizzle (correctness-proven r14/r15).
__device__ __forceinline__ void stage_granule(const char* src, _Float16* dst, int fb) {
    uint4 v = *(const uint4*)(src + fb);
    const int r = fb >> 11, c0 = (fb & 2047) >> 1;
    const int kiG = c0 >> 5, q = (c0 >> 3) & 3;
    const int ln = (r & 15) + 16 * q;
    const int pl = ln ^ ((ln >> 3) & 6) ^ (kiG & 1);
    *(uint4*)&dst[(((r >> 4) * 32 + kiG) * 64 + pl) * 8] = v;
}

// Stage a [1024 k] x [64 gate-col] fp32 weight slice into per-wave MFMA B-fragments.
__device__ __forceinline__ void load_wfrags(const float* M, int colbase, int myrow,
                                            int koff, bool keep, f16x8* wf, _Float16* st) {
    for (int kc = 0; kc < 4; ++kc) {
        __syncthreads();
        #pragma unroll
        for (int it = 0; it < 4; ++it) {
            int id  = it * NT + (int)threadIdx.x;
            int kl  = id >> 3, gc8 = id & 7;
            int gcol = (gc8 >> 1) * 1024 + colbase + (gc8 & 1) * 8;
            const float* src = M + (size_t)(kc * 256 + kl) * G4_ + gcol;
            float4 v0 = *(const float4*)src;
            float4 v1 = *(const float4*)(src + 4);
            int rb = gc8 * 8;
            st[(rb+0)*WROW+kl]=(_Float16)v0.x; st[(rb+1)*WROW+kl]=(_Float16)v0.y;
            st[(rb+2)*WROW+kl]=(_Float16)v0.z; st[(rb+3)*WROW+kl]=(_Float16)v0.w;
            st[(rb+4)*WROW+kl]=(_Float16)v1.x; st[(rb+5)*WROW+kl]=(_Float16)v1.y;
            st[(rb+6)*WROW+kl]=(_Float16)v1.z; st[(rb+7)*WROW+kl]=(_Float16)v1.w;
        }
        __syncthreads();
        if (keep) {
            #pragma unroll
            for (int kj = 0; kj < 8; ++kj)
                wf[kc*8+kj] = *(const f16x8*)&st[myrow * WROW + kj * 32 + koff];
        }
    }
    __syncthreads();
}

// flags: dom0 @ ctr[db*2+wv] (128), dom1 @ ctr[128+db*2+wv] (128), engine @ ctr[384+e] (64)

__global__ __launch_bounds__(NT, 1)
void lstm16(const float* __restrict__ x,
            const float* __restrict__ W0, const float* __restrict__ U0, const float* __restrict__ b0,
            const float* __restrict__ W1, const float* __restrict__ U1, const float* __restrict__ b1,
            _Float16* __restrict__ h1,       // [T][B][H] fp16
            _Float16* __restrict__ h2,       // [T][B][H] fp16
            _Float16* __restrict__ xzr,      // [4][8][B][4H] fp16 ring (b0 folded)
            const _Float16* __restrict__ zp, // [B][H] fp16 zeros
            unsigned* __restrict__ ctr,
            float* __restrict__ out)         // [B][H] fp32
{
    __shared__ __align__(16) char smem[148480];

    const int tid = threadIdx.x, bid = blockIdx.x;
    const int w = tid >> 6, l = tid & 63;
    const int koff = (l >> 4) * 8;
    const int pl0 = l ^ ((l >> 3) & 6);    // XOR-swizzled fragment lane (kiG even)

    // ============================ xz ENGINE (bid 128..191) ============================
    if (bid >= 128) {
        _Float16* Wl = (_Float16*)smem;
        const int e = bid - 128, gbase = e * 64;
        for (int fi = tid; fi < 16384; fi += NT) {
            const int k = fi >> 4, rem = fi & 15;
            const float* src = W0 + (size_t)k * G4_ + gbase + rem * 4;
            float4 v = *(const float4*)src;
            const int kiG = k >> 5, jsub = 16 * ((k & 31) >> 3), e8 = k & 7;
            #pragma unroll
            for (int c = 0; c < 4; ++c) {
                const int j = rem * 4 + c, nf = j >> 4, lane = (j & 15) + jsub;
                float fv = (c == 0) ? v.x : (c == 1) ? v.y : (c == 2) ? v.z : v.w;
                Wl[((nf * 32 + kiG) * 64 + lane) * 8 + e8] = (_Float16)fv;
            }
        }
        float bb0[4];
        #pragma unroll
        for (int nf = 0; nf < 4; ++nf) bb0[nf] = b0[gbase + nf * 16 + (l & 15)];
        __syncthreads();

        for (int c = 0; c < 64; ++c) {
            if (c >= 4) {   // ring-slot reuse guard: dom0 consumed chunk c-4
                if (w == 0) {
                    const unsigned need = (unsigned)(8 * c - 24);
                    while (true) {
                        unsigned v = umin2(ldA(&ctr[2 * l]), ldA(&ctr[2 * l + 1]));
                        if (__all((int)(v >= need))) break;
                        __builtin_amdgcn_s_sleep(1);
                    }
                }
                __syncthreads();
            }
            f32x4 acc[2][4];
            #pragma unroll
            for (int p = 0; p < 2; ++p)
                #pragma unroll
                for (int nf = 0; nf < 4; ++nf) acc[p][nf] = (f32x4){0.f, 0.f, 0.f, 0.f};
            const float* xrow[2];
            #pragma unroll
            for (int p = 0; p < 2; ++p) {
                const int m = (w * 2 + p) * 16 + (l & 15);
                xrow[p] = x + ((size_t)(m & 31) * T_ + (8 * c + (m >> 5))) * 1024;
            }
            #pragma unroll 4
            for (int kiG = 0; kiG < 32; ++kiG) {
                const int kk = kiG * 32 + koff;
                f16x8 af[2];
                #pragma unroll
                for (int p = 0; p < 2; ++p) {
                    float4 v0 = *(const float4*)&xrow[p][kk];
                    float4 v1 = *(const float4*)&xrow[p][kk + 4];
                    af[p][0]=(_Float16)v0.x; af[p][1]=(_Float16)v0.y;
                    af[p][2]=(_Float16)v0.z; af[p][3]=(_Float16)v0.w;
                    af[p][4]=(_Float16)v1.x; af[p][5]=(_Float16)v1.y;
                    af[p][6]=(_Float16)v1.z; af[p][7]=(_Float16)v1.w;
                }
                #pragma unroll
                for (int nf = 0; nf < 4; ++nf) {
                    f16x8 bf = *(const f16x8*)&Wl[((nf * 32 + kiG) * 64 + l) * 8];
                    acc[0][nf] = __builtin_amdgcn_mfma_f32_16x16x32_f16(af[0], bf, acc[0][nf], 0, 0, 0);
                    acc[1][nf] = __builtin_amdgcn_mfma_f32_16x16x32_f16(af[1], bf, acc[1][nf], 0, 0, 0);
                }
            }
            #pragma unroll
            for (int p = 0; p < 2; ++p)
                #pragma unroll
                for (int nf = 0; nf < 4; ++nf)
                    #pragma unroll
                    for (int i = 0; i < 4; ++i) {
                        _Float16 hf = (_Float16)(acc[p][nf][i] + bb0[nf]);
                        unsigned short us; __builtin_memcpy(&us, &hf, 2);
                        unsigned up = us;
                        unsigned op = (unsigned)__shfl_xor((int)up, 1);
                        if (!(l & 1)) {
                            const int m = (w * 2 + p) * 16 + (l >> 4) * 4 + i;
                            size_t off = (((size_t)(c & 3) * 8 + (m >> 5)) * B_ + (m & 31)) * G4_
                                       + gbase + nf * 16 + ((l & 15) & ~1);
                            stA32((unsigned*)&xzr[off], up | (op << 16));
                        }
                    }
            asm volatile("s_waitcnt vmcnt(0)" ::: "memory");
            __syncthreads();
            if (tid == 0) stA32(&ctr[384 + e], (unsigned)(c + 1));
        }
        return;
    }

    // ============================ RECURRENCE DOMAINS (64+64 blocks x 16 cols) ============================
    const int dom = (bid >= 64);
    const int db  = bid & 63;
    const int jb  = db * 16;

    _Float16* stA = (_Float16*)smem;                 // 64 KiB frag-order A (h1 side)
    _Float16* stB = (_Float16*)(smem + 65536);       // 64 KiB (dom1: h2 side)
    float*    red = (float*)(smem + (dom ? 131072 : 65536));
    #define RED(slot, row, col) red[((slot) * 16 + (row)) * 17 + (col)]

    f16x8 wf[32];
    const int gq = w & 3;
    const int myrow = gq * 16 + (l & 15);
    if (dom == 0) {
        load_wfrags(U0, jb, myrow, koff, true, wf, stA);
    } else {
        const int rl0 = w >> 2;
        load_wfrags(W1, jb, myrow, koff, (rl0 == 0), wf, stA);
        load_wfrags(U1, jb, myrow, koff, (rl0 == 1), wf, stA);
    }

    const int cidx = w * 64 + l;
    const int cb = cidx >> 2, j4 = (cidx & 3) * 4;
    float creg[4] = {0.f, 0.f, 0.f, 0.f};
    float bias_[4][4];
    if (dom == 1 && w < 2) {
        #pragma unroll
        for (int g = 0; g < 4; ++g)
            #pragma unroll
            for (int c = 0; c < 4; ++c)
                bias_[g][c] = b1[(size_t)g * H_ + jb + j4 + c];
    }
    const int mt = w >> 2;          // dom0 m-tile
    const int rl = w >> 2;          // dom1 role

    for (int t = 0; t < T_; ++t) {
        // ---- single polling wave (wave 0), lane-parallel over flag sets ----
        if (w == 0) {
            if (dom == 0) {
                const unsigned xt = (unsigned)((t >> 3) + 1);
                while (true) {
                    bool ok = (ldA(&ctr[384 + l]) >= xt);
                    if (t > 0) {
                        unsigned v0 = umin2(ldA(&ctr[2 * l]), ldA(&ctr[2 * l + 1]));
                        ok = ok && (v0 >= (unsigned)t);
                    }
                    if (__all((int)ok)) break;
                    __builtin_amdgcn_s_sleep(1);
                }
            } else {
                while (true) {
                    unsigned v0 = umin2(ldA(&ctr[2 * l]), ldA(&ctr[2 * l + 1]));
                    bool ok = (v0 >= (unsigned)(t + 1));
                    if (t > 0) {
                        unsigned v1 = umin2(ldA(&ctr[128 + 2 * l]), ldA(&ctr[128 + 2 * l + 1]));
                        ok = ok && (v1 >= (unsigned)t);
                    }
                    if (__all((int)ok)) break;
                    __builtin_amdgcn_s_sleep(1);
                }
            }
        }
        __syncthreads();   // S1: dependencies published+ACKed, staging buffers free

        // ---- block-cooperative frag-order staging (coalesced global reads) ----
        if (dom == 0) {
            const char* src = t ? (const char*)(h1 + (size_t)(t - 1) * B_ * H_) : (const char*)zp;
            #pragma unroll
            for (int it = 0; it < 8; ++it)
                stage_granule(src, stA, tid * 16 + it * 8192);
        } else {
            const char* s1 = (const char*)(h1 + (size_t)t * B_ * H_);
            const char* s2 = t ? (const char*)(h2 + (size_t)(t - 1) * B_ * H_) : (const char*)zp;
            #pragma unroll
            for (int it = 0; it < 8; ++it) {
                stage_granule(s1, stA, tid * 16 + it * 8192);
                stage_granule(s2, stB, tid * 16 + it * 8192);
            }
        }
        // dom0 combine waves: issue xz bypass loads (consumed after S3)
        unsigned long long xzq[4];
        if (dom == 0 && w < 2) {
            const size_t xbase = (((size_t)((t >> 3) & 3) * 8 + (t & 7)) * B_ + cb) * G4_ + jb + j4;
            #pragma unroll
            for (int gg = 0; gg < 4; ++gg) xzq[gg] = ldA64(&xzr[xbase + gg * 1024]);
        }
        __syncthreads();   // S2: stage visible

        // ---- MFMA: frag-order A reads (linear lane*16B + XOR; conflict-free) ----
        if (dom == 0) {
            f32x4 ac0 = {0,0,0,0}, ac1 = {0,0,0,0};
            #pragma unroll
            for (int k = 0; k < 32; k += 2) {
                ac0 = __builtin_amdgcn_mfma_f32_16x16x32_f16(
                    *(const f16x8*)&stA[((mt * 32 + k) * 64 + pl0) * 8], wf[k], ac0, 0, 0, 0);
                ac1 = __builtin_amdgcn_mfma_f32_16x16x32_f16(
                    *(const f16x8*)&stA[((mt * 32 + k + 1) * 64 + (pl0 ^ 1)) * 8], wf[k + 1], ac1, 0, 0, 0);
            }
            f32x4 acc = ac0 + ac1;
            #pragma unroll
            for (int i = 0; i < 4; ++i)
                RED(mt * 4 + gq, (l >> 4) * 4 + i, (l & 15)) = acc[i];
        } else {
            const _Float16* ab = (rl ? stB : stA);
            f32x4 ac0 = {0,0,0,0}, ac1 = {0,0,0,0};
            #pragma unroll
            for (int k = 0; k < 32; ++k) {
                const int pl = pl0 ^ (k & 1);
                f16x8 bfr = wf[k];
                ac0 = __builtin_amdgcn_mfma_f32_16x16x32_f16(
                    *(const f16x8*)&ab[((0 * 32 + k) * 64 + pl) * 8], bfr, ac0, 0, 0, 0);
                ac1 = __builtin_amdgcn_mfma_f32_16x16x32_f16(
                    *(const f16x8*)&ab[((1 * 32 + k) * 64 + pl) * 8], bfr, ac1, 0, 0, 0);
            }
            #pragma unroll
            for (int i = 0; i < 4; ++i) {
                RED(rl * 8 + 0 * 4 + gq, (l >> 4) * 4 + i, (l & 15)) = ac0[i];
                RED(rl * 8 + 1 * 4 + gq, (l >> 4) * 4 + i, (l & 15)) = ac1[i];
            }
        }
        __syncthreads();   // S3: red ready, stage buffers free

        // ---- combine + state + publish + ACK + flag (waves 0..1) ----
        if (w < 2) {
            const int rmt = cb >> 4, row = cb & 15;
            unsigned long long pk = 0;
            float hv4[4];
            if (dom == 0) {
                asm volatile("s_waitcnt vmcnt(0)" ::: "memory");   // xz loads landed
                #pragma unroll
                for (int c = 0; c < 4; ++c) {
                    float z[4];
                    #pragma unroll
                    for (int gg = 0; gg < 4; ++gg) {
                        float xv = f16bits_to_f((unsigned short)((xzq[gg] >> (16 * c)) & 0xffffu));
                        z[gg] = RED(rmt * 4 + gg, row, j4 + c) + xv;   // b0 folded in xz
                    }
                    float ig = hardsig(z[0]), fg = hardsig(z[1]);
                    float gv = fast_tanh(z[2]), og = hardsig(z[3]);
                    creg[c] = fg * creg[c] + ig * gv;
                    hv4[c] = og * fast_tanh(creg[c]);
                    _Float16 hf = (_Float16)hv4[c];
                    unsigned short us; __builtin_memcpy(&us, &hf, 2);
                    pk |= ((unsigned long long)us) << (16 * c);
                }
                stA64(&h1[((size_t)t * B_ + cb) * H_ + jb + j4], pk);
                asm volatile("s_waitcnt vmcnt(0)" ::: "memory");   // publish ACKed at LLC
                if (l == 0) stA32(&ctr[db * 2 + w], (unsigned)(t + 1));
            } else {
                #pragma unroll
                for (int c = 0; c < 4; ++c) {
                    float z[4];
                    #pragma unroll
                    for (int gg = 0; gg < 4; ++gg)
                        z[gg] = RED(0 + rmt * 4 + gg, row, j4 + c)
                              + RED(8 + rmt * 4 + gg, row, j4 + c) + bias_[gg][c];
                    float ig = hardsig(z[0]), fg = hardsig(z[1]);
                    float gv = fast_tanh(z[2]), og = hardsig(z[3]);
                    creg[c] = fg * creg[c] + ig * gv;
                    hv4[c] = og * fast_tanh(creg[c]);
                    _Float16 hf = (_Float16)hv4[c];
                    unsigned short us; __builtin_memcpy(&us, &hf, 2);
                    pk |= ((unsigned long long)us) << (16 * c);
                }
                stA64(&h2[((size_t)t * B_ + cb) * H_ + jb + j4], pk);
                if (t == T_ - 1)
                    *(float4*)&out[(size_t)cb * H_ + jb + j4] = make_float4(hv4[0], hv4[1], hv4[2], hv4[3]);
                asm volatile("s_waitcnt vmcnt(0)" ::: "memory");
                if (l == 0) stA32(&ctr[128 + db * 2 + w], (unsigned)(t + 1));
            }
        }
    }
}

extern "C" void kernel_launch(void* const* d_in, const int* in_sizes, int n_in,
                              void* d_out, int out_size, void* d_ws, size_t ws_size,
                              hipStream_t stream) {
    const float* x  = (const float*)d_in[0];
    const float* W0 = (const float*)d_in[1];
    const float* U0 = (const float*)d_in[2];
    const float* b0 = (const float*)d_in[3];
    const float* W1 = (const float*)d_in[4];
    const float* U1 = (const float*)d_in[5];
    const float* b1 = (const float*)d_in[6];
    float* out = (float*)d_out;

    char* ws = (char*)d_ws;
    const size_t off_h1 = 0;          // 32 MiB  h1 fp16 [T][B][H]
    const size_t off_h2 = 33554432;   // 32 MiB  h2 fp16 [T][B][H]
    const size_t off_xz = 67108864;   //  8 MiB  xz ring fp16
    const size_t off_zp = 75497472;   // 64 KiB  fp16 zeros
    const size_t off_ct = 75563008;   //  8 KiB  flags

    _Float16* h1  = (_Float16*)(ws + off_h1);
    _Float16* h2  = (_Float16*)(ws + off_h2);
    _Float16* xzr = (_Float16*)(ws + off_xz);
    _Float16* zp  = (_Float16*)(ws + off_zp);
    unsigned* ctr = (unsigned*)(ws + off_ct);

    // zero zp + flags every launch (graph-capture safe)
    hipMemsetAsync(ws + off_zp, 0, 65536 + 8192, stream);

    hipLaunchKernelGGL(lstm16, dim3(192), dim3(NT), 0, stream,
                       x, W0, U0, b0, W1, U1, b1,
                       h1, h2, xzr, zp, ctr, out);
}